// Round 6
// baseline (1096.423 us; speedup 1.0000x reference)
//
#include <hip/hip_runtime.h>
#include <hip/hip_fp16.h>
#include <cmath>
#include <cstdint>

// HashPINN R15:
//  - R14 analysis: hashed encode sits exactly at the per-CU MSHR wall
//    (19.5K lines/CU x 3.9cy = the measured 31-32us/dispatch). Levers:
//    fewer lines, fewer serialized phases.
//  - 32B hash windows (8 fp16 entries, 32B-aligned => always exactly 1
//    line): pair (ix,ix+1) splits a window only when ix&7==7 -> extra-load
//    prob 1/4 -> 1/8 => 5 -> 4.5 lines/pt (-10%). TA/VALU ~<10% busy so the
//    doubled window-load count and sel8 cndmask tree are free. encode at
//    (256,4): MSHR saturation needs only ~64 in-flight lines/CU; 16 waves
//    oversubscribe it, and the 128-reg budget avoids spills.
//  - Dense levels (0..dense_end-1, 2.2MB of tables, L1/L2-hot) fused into
//    the MLP kernel: mlp is NOT MSHR-bound (streaming featT + compute), so
//    its idle miss-queue absorbs the dense gathers; removes 2 dense encode
//    dispatches and shrinks featT to 10 hashed levels (80MB/half). Gathered
//    features are bit-identical to the staged path (same fp16+pack_split2).
//  - Everything else (two-half schedule, permlane exchange MLP, fallbacks)
//    unchanged from R14.

#define HASH_SZ (1u << 19)
#define HMASK   (HASH_SZ - 1u)
#define PR2 2654435761u
#define PR3 805459861u

typedef float v2f __attribute__((ext_vector_type(2)));
typedef float v4f __attribute__((ext_vector_type(4)));
typedef v4f v4fu __attribute__((aligned(8)));
typedef v2f v2fu __attribute__((aligned(8)));
typedef short bf16x8 __attribute__((ext_vector_type(8)));
typedef float f32x4 __attribute__((ext_vector_type(4)));
typedef unsigned int u32;
typedef u32 u32x2 __attribute__((ext_vector_type(2)));
typedef u32 u32x4 __attribute__((ext_vector_type(4)));
typedef u32x4 u32x4u __attribute__((aligned(8)));

struct ResArr { int r[16]; };

// ---------- bf16 helpers ----------
__device__ __forceinline__ unsigned short bf16_rne(float f) {
    union { float f; unsigned u; } v; v.f = f;
    unsigned u = v.u;
    unsigned r = (u + 0x7fffu + ((u >> 16) & 1u)) >> 16;
    return (unsigned short)r;
}
__device__ __forceinline__ float bf16f(unsigned short h) {
    union { unsigned u; float f; } v; v.u = ((unsigned)h) << 16;
    return v.f;
}
// hi = TRUNCATED bf16 (cheap); lo = RNE bf16 of the exact remainder.
__device__ __forceinline__ void split8(const float* x, bf16x8& hi, bf16x8& lo) {
    #pragma unroll
    for (int j = 0; j < 8; ++j) {
        union { float f; unsigned u; } v; v.f = x[j];
        const unsigned hu = v.u & 0xffff0000u;
        hi[j] = (short)(hu >> 16);
        union { unsigned u; float f; } hf; hf.u = hu;
        const float d = x[j] - hf.f;
        union { float f; unsigned u; } dv; dv.f = d;
        lo[j] = (short)((dv.u + 0x7fffu + ((dv.u >> 16) & 1u)) >> 16);
    }
}
__device__ __forceinline__ u32 rne16u(float f) {
    union { float f; u32 u; } v; v.f = f;
    return (v.u + 0x7fffu + ((v.u >> 16) & 1u)) >> 16;
}
// pack two features into {hi0|hi1<<16, lo0|lo1<<16} (bit-identical to split8)
__device__ __forceinline__ u32x2 pack_split2(float f0, float f1) {
    union { float f; u32 u; } a, b; a.f = f0; b.f = f1;
    const u32 h0 = a.u & 0xffff0000u, h1 = b.u & 0xffff0000u;
    union { u32 u; float f; } ha, hb; ha.u = h0; hb.u = h1;
    u32x2 r;
    r.x = (h0 >> 16) | h1;
    r.y = rne16u(f0 - ha.f) | (rne16u(f1 - hb.f) << 16);
    return r;
}

// ---------- fp16 helpers ----------
__device__ __forceinline__ u32 pkh(float f0, float f1) {
    const __half h0 = __float2half_rn(f0), h1 = __float2half_rn(f1);
    return (u32)__half_as_ushort(h0) | ((u32)__half_as_ushort(h1) << 16);
}
__device__ __forceinline__ v2f cvt2(u32 e) {
    __half2 h;
    *reinterpret_cast<u32*>(&h) = e;
    v2f r; r.x = __low2float(h); r.y = __high2float(h);
    return r;
}
// select entry k (0..7) from a 32B window (two u32x4), static indices only
__device__ __forceinline__ u32 sel8(u32x4 lo, u32x4 hi, u32 k) {
    const u32 a = (k & 1u) ? lo.y : lo.x;
    const u32 b = (k & 1u) ? lo.w : lo.z;
    const u32 c = (k & 1u) ? hi.y : hi.x;
    const u32 d = (k & 1u) ? hi.w : hi.z;
    const u32 e = (k & 2u) ? b : a;
    const u32 f = (k & 2u) ? d : c;
    return (k & 4u) ? f : e;
}

// ---------------- table conversion: fp32 pairs -> packed fp16 ----------------
__global__ __launch_bounds__(256, 8)
void cvt_table(const float* __restrict__ table, u32* __restrict__ tab16, int total)
{
    const int e0 = (blockIdx.x * 256 + threadIdx.x) * 4;
    if (e0 >= total) return;
    const v4f a = __builtin_nontemporal_load((const v4f*)(table + 2 * (size_t)e0));
    const v4f b = __builtin_nontemporal_load((const v4f*)(table + 2 * (size_t)e0 + 4));
    u32x4 o;
    o.x = pkh(a.x, a.y); o.y = pkh(a.z, a.w);
    o.z = pkh(b.x, b.y); o.w = pkh(b.z, b.w);
    *(u32x4*)(tab16 + e0) = o;
}

// ---------------- hashed fp16 gather, 32B windows ----------------
__device__ __forceinline__ void gather16h(
    const u32* __restrict__ tab, int res,
    float px, float py, float pz, float& A0, float& A1)
{
    const float rf = (float)(res - 1);
    const float fx = px * rf, fy = py * rf, fz = pz * rf;
    int ix = (int)floorf(fx), iy = (int)floorf(fy), iz = (int)floorf(fz);
    ix = min(max(ix, 0), res - 2);
    iy = min(max(iy, 0), res - 2);
    iz = min(max(iz, 0), res - 2);
    const float tx = fx - (float)ix, ty = fy - (float)iy, tz = fz - (float)iz;
    const float sx = 1.f - tx, sy = 1.f - ty, sz = 1.f - tz;
    float a0 = 0.f, a1 = 0.f;

    u32 i1a[4], k0[4];
    u32x4 lo[4], hi[4];
    #pragma unroll
    for (int c = 0; c < 4; ++c) {
        const int dy = c >> 1, dz = c & 1;
        const u32 r = (u32)(iy + dy) * PR2 ^ (u32)(iz + dz) * PR3;
        const u32 i0 = ((u32)ix ^ r) & HMASK;
        i1a[c] = ((u32)(ix + 1) ^ r) & HMASK;
        k0[c] = i0 & 7u;
        const u32 base = i0 & ~7u;
        lo[c] = *(const u32x4*)(tab + base);
        hi[c] = *(const u32x4*)(tab + base + 4);
    }
    const bool extra = ((ix & 7) == 7);   // (ix^(ix+1)) spans the 8-window
    u32 O[4];
    if (extra) {
        #pragma unroll
        for (int c = 0; c < 4; ++c) O[c] = tab[i1a[c]];
    } else {
        #pragma unroll
        for (int c = 0; c < 4; ++c) O[c] = 0u;
    }
    #pragma unroll
    for (int c = 0; c < 4; ++c) {
        const int dy = c >> 1, dz = c & 1;
        const u32 e0 = sel8(lo[c], hi[c], k0[c]);
        const u32 e1w = sel8(lo[c], hi[c], i1a[c] & 7u);
        const u32 e1 = extra ? O[c] : e1w;
        const float wyz = (dy ? ty : sy) * (dz ? tz : sz);
        const float w0 = sx * wyz, w1 = tx * wyz;
        const v2f f0 = cvt2(e0), f1 = cvt2(e1);
        a0 = fmaf(w0, f0.x, a0); a1 = fmaf(w0, f0.y, a1);
        a0 = fmaf(w1, f1.x, a0); a1 = fmaf(w1, f1.y, a1);
    }
    A0 = a0; A1 = a1;
}

// ---------------- dense fp16 gather (used inside fused MLP) ----------------
__device__ __forceinline__ void gather16d(
    const u32* __restrict__ tab, int res,
    float px, float py, float pz, float& A0, float& A1)
{
    const float rf = (float)(res - 1);
    const float fx = px * rf, fy = py * rf, fz = pz * rf;
    int ix = (int)floorf(fx), iy = (int)floorf(fy), iz = (int)floorf(fz);
    ix = min(max(ix, 0), res - 2);
    iy = min(max(iy, 0), res - 2);
    iz = min(max(iz, 0), res - 2);
    const float tx = fx - (float)ix, ty = fy - (float)iy, tz = fz - (float)iz;
    const float sx = 1.f - tx, sy = 1.f - ty, sz = 1.f - tz;
    float a0 = 0.f, a1 = 0.f;
    const int b0 = ix + res * (iy + res * iz);
    #pragma unroll
    for (int c = 0; c < 4; ++c) {
        const int dy = c >> 1, dz = c & 1;
        const u32 idx0 = (u32)(b0 + res * dy + res * res * dz);
        const u32x4u Pv = *(const u32x4u*)(tab + (idx0 & ~1u));
        const bool hh = (idx0 & 1u) != 0u;
        const u32 e0 = hh ? Pv.y : Pv.x;
        const u32 e1 = hh ? Pv.z : Pv.y;
        const float wyz = (dy ? ty : sy) * (dz ? tz : sz);
        const float w0 = sx * wyz, w1 = tx * wyz;
        const v2f f0 = cvt2(e0), f1 = cvt2(e1);
        a0 = fmaf(w0, f0.x, a0); a1 = fmaf(w0, f0.y, a1);
        a0 = fmaf(w1, f1.x, a0); a1 = fmaf(w1, f1.y, a1);
    }
    A0 = a0; A1 = a1;
}

// ---------------- hashed-level encode (single level per dispatch) ----------------
__global__ __launch_bounds__(256, 4)
void encode16h_k(const float* __restrict__ x, const u32* __restrict__ tbl,
                 u32x2* __restrict__ featT, int n, int ns, int slot, int res)
{
    const int nth2 = gridDim.x * 512;
    for (int q = (blockIdx.x * 256 + threadIdx.x) * 2; q < n; q += nth2) {
        float p0x, p0y, p0z, p1x, p1y, p1z;
        const bool two = (q + 1 < n);
        if (two) {
            const v4fu a = __builtin_nontemporal_load((const v4fu*)(x + 3 * q));
            const v2f  b = __builtin_nontemporal_load((const v2fu*)(x + 3 * q + 4));
            p0x = a.x; p0y = a.y; p0z = a.z; p1x = a.w; p1y = b.x; p1z = b.y;
        } else {
            p0x = x[3 * q]; p0y = x[3 * q + 1]; p0z = x[3 * q + 2];
            p1x = p0x; p1y = p0y; p1z = p0z;
        }
        float a00, a01, a10, a11;
        gather16h(tbl, res, p0x, p0y, p0z, a00, a01);
        gather16h(tbl, res, p1x, p1y, p1z, a10, a11);
        if (two) {
            const u32x2 e0 = pack_split2(a00, a01);
            const u32x2 e1 = pack_split2(a10, a11);
            u32x4 st; st.x = e0.x; st.y = e0.y; st.z = e1.x; st.w = e1.y;
            __builtin_nontemporal_store(st, (u32x4*)&featT[(size_t)slot * ns + q]);
        } else {
            __builtin_nontemporal_store(pack_split2(a00, a01),
                                        &featT[(size_t)slot * ns + q]);
        }
    }
}

// ---------------- fp32 encode (ws-fallback path) ----------------
__device__ __forceinline__ void gather_one(
    const v2f* __restrict__ tbl, int res, bool dense,
    float px, float py, float pz, float& A0, float& A1)
{
    const float rf = (float)(res - 1);
    const float fx = px * rf, fy = py * rf, fz = pz * rf;
    int ix = (int)floorf(fx), iy = (int)floorf(fy), iz = (int)floorf(fz);
    ix = min(max(ix, 0), res - 2);
    iy = min(max(iy, 0), res - 2);
    iz = min(max(iz, 0), res - 2);
    const float tx = fx - (float)ix, ty = fy - (float)iy, tz = fz - (float)iz;
    const float sx = 1.f - tx, sy = 1.f - ty, sz = 1.f - tz;
    float a0 = 0.f, a1 = 0.f;

    if (dense) {
        const int b0 = ix + res * (iy + res * iz);
        v4fu P[4];
        #pragma unroll
        for (int c = 0; c < 4; ++c) {
            const int dy = c >> 1, dz = c & 1;
            P[c] = *(const v4fu*)((const float*)tbl + 2 * (b0 + res * dy + res * res * dz));
        }
        #pragma unroll
        for (int c = 0; c < 4; ++c) {
            const int dy = c >> 1, dz = c & 1;
            const float wyz = (dy ? ty : sy) * (dz ? tz : sz);
            const float w0 = sx * wyz, w1 = tx * wyz;
            a0 = fmaf(w0, P[c].x, a0); a1 = fmaf(w0, P[c].y, a1);
            a0 = fmaf(w1, P[c].z, a0); a1 = fmaf(w1, P[c].w, a1);
        }
    } else {
        uint32_t i0[4], i1[4];
        v4f P[4];
        #pragma unroll
        for (int c = 0; c < 4; ++c) {
            const int dy = c >> 1, dz = c & 1;
            const uint32_t r = (uint32_t)(iy + dy) * PR2 ^ (uint32_t)(iz + dz) * PR3;
            i0[c] = ((uint32_t)ix ^ r) & HMASK;
            i1[c] = ((uint32_t)(ix + 1) ^ r) & HMASK;
            P[c] = *(const v4f*)((const float*)tbl + 2 * (i0[c] & ~1u));
        }
        const bool odd = (ix & 1);
        v2f O[4];
        if (odd) {
            #pragma unroll
            for (int c = 0; c < 4; ++c) O[c] = tbl[i1[c]];
        } else {
            #pragma unroll
            for (int c = 0; c < 4; ++c) { v2f z = {0.f, 0.f}; O[c] = z; }
        }
        #pragma unroll
        for (int c = 0; c < 4; ++c) {
            const int dy = c >> 1, dz = c & 1;
            const bool hi = (i0[c] & 1);
            v2f c0, e;
            c0.x = hi ? P[c].z : P[c].x;  c0.y = hi ? P[c].w : P[c].y;
            e.x  = hi ? P[c].x : P[c].z;  e.y  = hi ? P[c].y : P[c].w;
            const v2f c1 = odd ? O[c] : e;
            const float wyz = (dy ? ty : sy) * (dz ? tz : sz);
            const float w0 = sx * wyz, w1 = tx * wyz;
            a0 = fmaf(w0, c0.x, a0); a1 = fmaf(w0, c0.y, a1);
            a0 = fmaf(w1, c1.x, a0); a1 = fmaf(w1, c1.y, a1);
        }
    }
    A0 = a0; A1 = a1;
}

template<int NLEV>
__global__ __launch_bounds__(256, 8)
void encode_k(const float* __restrict__ x, const float* __restrict__ table,
              u32x2* __restrict__ featT, int n, int lb, ResArr rv)
{
    const int nth2 = gridDim.x * 512;
    for (int q = (blockIdx.x * 256 + threadIdx.x) * 2; q < n; q += nth2) {
        float p0x, p0y, p0z, p1x, p1y, p1z;
        const bool two = (q + 1 < n);
        if (two) {
            const v4fu a = __builtin_nontemporal_load((const v4fu*)(x + 3 * q));
            const v2f  b = __builtin_nontemporal_load((const v2fu*)(x + 3 * q + 4));
            p0x = a.x; p0y = a.y; p0z = a.z; p1x = a.w; p1y = b.x; p1z = b.y;
        } else {
            p0x = x[3 * q]; p0y = x[3 * q + 1]; p0z = x[3 * q + 2];
            p1x = p0x; p1y = p0y; p1z = p0z;
        }
        #pragma unroll
        for (int il = 0; il < NLEV; ++il) {
            const int l = lb + il;
            const int res = rv.r[l];
            const bool dense = ((long long)res * res * res <= (long long)HASH_SZ);
            const v2f* tbl = (const v2f*)table + (size_t)l * HASH_SZ;
            float a00, a01, a10, a11;
            gather_one(tbl, res, dense, p0x, p0y, p0z, a00, a01);
            gather_one(tbl, res, dense, p1x, p1y, p1z, a10, a11);
            if (two) {
                const u32x2 e0 = pack_split2(a00, a01);
                const u32x2 e1 = pack_split2(a10, a11);
                u32x4 st; st.x = e0.x; st.y = e0.y; st.z = e1.x; st.w = e1.y;
                __builtin_nontemporal_store(st, (u32x4*)&featT[(size_t)l * n + q]);
            } else {
                __builtin_nontemporal_store(pack_split2(a00, a01),
                                            &featT[(size_t)l * n + q]);
            }
        }
    }
}

// ---------------- weight prep (layout doubles as A-operand frags) ----------------
__global__ void prep_weights(const float* __restrict__ W1,
                             const float* __restrict__ W2,
                             const float* __restrict__ W3,
                             unsigned short* __restrict__ wb)
{
    const int tid = threadIdx.x;
    const int nb = tid >> 6, lane = tid & 63;
    const int l15 = lane & 15, q = lane >> 4;
    #pragma unroll
    for (int j = 0; j < 8; ++j) {
        const float v = W1[(q * 8 + j) * 64 + nb * 16 + l15];
        const unsigned short h = bf16_rne(v);
        wb[(nb * 64 + lane) * 8 + j] = h;
        wb[2048 + (nb * 64 + lane) * 8 + j] = bf16_rne(v - bf16f(h));
    }
    #pragma unroll
    for (int kb = 0; kb < 2; ++kb) {
        #pragma unroll
        for (int j = 0; j < 8; ++j) {
            const int row = kb * 32 + q * 8 + j;
            const int idx = ((kb * 4 + nb) * 64 + lane) * 8 + j;
            float v = W2[row * 64 + nb * 16 + l15];
            unsigned short h = bf16_rne(v);
            wb[4096 + idx] = h;
            wb[8192 + idx] = bf16_rne(v - bf16f(h));
            v = W3[row * 64 + nb * 16 + l15];
            h = bf16_rne(v);
            wb[12288 + idx] = h;
            wb[16384 + idx] = bf16_rne(v - bf16f(h));
        }
    }
}

// ---------------- fused MFMA MLP: dense gathers in-kernel, hashed from featT ----------------
__global__ __launch_bounds__(256, 4)
void mlp_mfma_f(const u32x2* __restrict__ featT,
                const unsigned short* __restrict__ wb,
                const float* __restrict__ b1, const float* __restrict__ b2,
                const float* __restrict__ b3,
                const float* __restrict__ Wo, const float* __restrict__ bo,
                float* __restrict__ out, int n, int ns,
                const float* __restrict__ xh, const u32* __restrict__ tab16,
                ResArr rv, int de)
{
    const int wave = threadIdx.x >> 6;
    const int lane = threadIdx.x & 63;
    const int l15 = lane & 15, quad = lane >> 4;
    const int p0 = (blockIdx.x * 4 + wave) * 32;
    if (p0 >= n) return;

    // ---- layer 1: lane (quad,jj) supplies level quad*4+jj for point l15 ----
    bf16x8 bh[2], bl[2];
    #pragma unroll
    for (int t = 0; t < 2; ++t) {
        const int p = p0 + t * 16 + l15;
        const int pl = (p < n) ? p : (n - 1);
        const float px = xh[3 * pl], py = xh[3 * pl + 1], pz = xh[3 * pl + 2];
        u32 hw[4], lw[4];
        #pragma unroll
        for (int jj = 0; jj < 4; ++jj) {
            const int lvl = quad * 4 + jj;
            if (lvl < de) {
                float a0, a1;
                gather16d(tab16 + (size_t)lvl * HASH_SZ, rv.r[lvl], px, py, pz, a0, a1);
                const u32x2 e = pack_split2(a0, a1);
                hw[jj] = e.x; lw[jj] = e.y;
            } else {
                const u32x2 v = featT[(size_t)(lvl - de) * ns + pl];
                hw[jj] = v.x; lw[jj] = v.y;
            }
        }
        u32x4 hwv, lwv;
        hwv.x = hw[0]; hwv.y = hw[1]; hwv.z = hw[2]; hwv.w = hw[3];
        lwv.x = lw[0]; lwv.y = lw[1]; lwv.z = lw[2]; lwv.w = lw[3];
        bh[t] = *(bf16x8*)&hwv;
        bl[t] = *(bf16x8*)&lwv;
    }

    f32x4 acc[2][4];
    #pragma unroll
    for (int nb = 0; nb < 4; ++nb) {
        const bf16x8 wh = *(const bf16x8*)(wb + (nb * 64 + lane) * 8);
        const bf16x8 wl = *(const bf16x8*)(wb + 2048 + (nb * 64 + lane) * 8);
        const f32x4 bv = *(const f32x4*)(b1 + nb * 16 + quad * 4);
        #pragma unroll
        for (int t = 0; t < 2; ++t) {
            f32x4 c = bv;
            c = __builtin_amdgcn_mfma_f32_16x16x32_bf16(wh, bl[t], c, 0, 0, 0);
            c = __builtin_amdgcn_mfma_f32_16x16x32_bf16(wl, bh[t], c, 0, 0, 0);
            c = __builtin_amdgcn_mfma_f32_16x16x32_bf16(wh, bh[t], c, 0, 0, 0);
            acc[t][nb] = c;
        }
    }

    // ---- hidden layers 2 & 3 (permlane exchange, verified R12) ----
    #pragma unroll
    for (int layer = 0; layer < 2; ++layer) {
        bf16x8 nh[2][2], nl[2][2];
        #pragma unroll
        for (int t = 0; t < 2; ++t) {
            #pragma unroll
            for (int kb = 0; kb < 2; ++kb) {
                float v[8];
                #pragma unroll
                for (int rr = 0; rr < 4; ++rr) {
                    float xq = fmaxf(acc[t][2 * kb][rr],     0.f);
                    float yq = fmaxf(acc[t][2 * kb + 1][rr], 0.f);
                    asm("v_permlane32_swap_b32 %0, %1" : "+v"(xq), "+v"(yq));
                    asm("v_permlane16_swap_b32 %0, %1" : "+v"(xq), "+v"(yq));
                    v[rr]     = xq;   // k = quad*8 + rr
                    v[4 + rr] = yq;   // k = quad*8 + 4 + rr
                }
                split8(v, nh[t][kb], nl[t][kb]);
            }
        }
        const int base_h = layer ? 12288 : 4096;
        const int base_l = layer ? 16384 : 8192;
        const float* __restrict__ bias = layer ? b3 : b2;
        #pragma unroll
        for (int nb = 0; nb < 4; ++nb) {
            const f32x4 bv = *(const f32x4*)(bias + nb * 16 + quad * 4);
            f32x4 c[2];
            #pragma unroll
            for (int t = 0; t < 2; ++t) c[t] = bv;
            #pragma unroll
            for (int kb = 0; kb < 2; ++kb) {
                const int idx = ((kb * 4 + nb) * 64 + lane) * 8;
                const bf16x8 wh = *(const bf16x8*)(wb + base_h + idx);
                const bf16x8 wl = *(const bf16x8*)(wb + base_l + idx);
                #pragma unroll
                for (int t = 0; t < 2; ++t) {
                    c[t] = __builtin_amdgcn_mfma_f32_16x16x32_bf16(wh, nl[t][kb], c[t], 0, 0, 0);
                    c[t] = __builtin_amdgcn_mfma_f32_16x16x32_bf16(wl, nh[t][kb], c[t], 0, 0, 0);
                    c[t] = __builtin_amdgcn_mfma_f32_16x16x32_bf16(wh, nh[t][kb], c[t], 0, 0, 0);
                }
            }
            #pragma unroll
            for (int t = 0; t < 2; ++t) acc[t][nb] = c[t];
        }
    }

    // ---- output layer ----
    float part[2];
    #pragma unroll
    for (int t = 0; t < 2; ++t) {
        float s = 0.f;
        #pragma unroll
        for (int nb = 0; nb < 4; ++nb) {
            const f32x4 wo4 = *(const f32x4*)(Wo + nb * 16 + quad * 4);
            #pragma unroll
            for (int r = 0; r < 4; ++r)
                s = fmaf(fmaxf(acc[t][nb][r], 0.f), wo4[r], s);
        }
        part[t] = s;
    }
    #pragma unroll
    for (int t = 0; t < 2; ++t) {
        part[t] += __shfl_xor(part[t], 16, 64);
        part[t] += __shfl_xor(part[t], 32, 64);
    }
    if (quad == 0) {
        const float b = bo[0];
        #pragma unroll
        for (int t = 0; t < 2; ++t) {
            const int po = p0 + t * 16 + l15;
            if (po < n) out[po] = part[t] + b;
        }
    }
}

// ---------------- non-fused MFMA MLP (R12 fallback: 16-level fp32-split featT) ----------------
__global__ __launch_bounds__(256, 4)
void mlp_mfma(const u32x2* __restrict__ featT,
              const unsigned short* __restrict__ wb,
              const float* __restrict__ b1, const float* __restrict__ b2,
              const float* __restrict__ b3,
              const float* __restrict__ Wo, const float* __restrict__ bo,
              float* __restrict__ out, int n, int ns)
{
    const int wave = threadIdx.x >> 6;
    const int lane = threadIdx.x & 63;
    const int l15 = lane & 15, quad = lane >> 4;
    const int p0 = (blockIdx.x * 4 + wave) * 32;
    if (p0 >= n) return;

    bf16x8 bh[2], bl[2];
    #pragma unroll
    for (int t = 0; t < 2; ++t) {
        const int p = p0 + t * 16 + l15;
        const int pl = (p < n) ? p : (n - 1);
        u32x4 hw, lw;
        #pragma unroll
        for (int jj = 0; jj < 4; ++jj) {
            const u32x2 v = featT[(size_t)(quad * 4 + jj) * ns + pl];
            hw[jj] = v.x; lw[jj] = v.y;
        }
        bh[t] = *(bf16x8*)&hw;
        bl[t] = *(bf16x8*)&lw;
    }

    f32x4 acc[2][4];
    #pragma unroll
    for (int nb = 0; nb < 4; ++nb) {
        const bf16x8 wh = *(const bf16x8*)(wb + (nb * 64 + lane) * 8);
        const bf16x8 wl = *(const bf16x8*)(wb + 2048 + (nb * 64 + lane) * 8);
        const f32x4 bv = *(const f32x4*)(b1 + nb * 16 + quad * 4);
        #pragma unroll
        for (int t = 0; t < 2; ++t) {
            f32x4 c = bv;
            c = __builtin_amdgcn_mfma_f32_16x16x32_bf16(wh, bl[t], c, 0, 0, 0);
            c = __builtin_amdgcn_mfma_f32_16x16x32_bf16(wl, bh[t], c, 0, 0, 0);
            c = __builtin_amdgcn_mfma_f32_16x16x32_bf16(wh, bh[t], c, 0, 0, 0);
            acc[t][nb] = c;
        }
    }

    #pragma unroll
    for (int layer = 0; layer < 2; ++layer) {
        bf16x8 nh[2][2], nl[2][2];
        #pragma unroll
        for (int t = 0; t < 2; ++t) {
            #pragma unroll
            for (int kb = 0; kb < 2; ++kb) {
                float v[8];
                #pragma unroll
                for (int rr = 0; rr < 4; ++rr) {
                    float xq = fmaxf(acc[t][2 * kb][rr],     0.f);
                    float yq = fmaxf(acc[t][2 * kb + 1][rr], 0.f);
                    asm("v_permlane32_swap_b32 %0, %1" : "+v"(xq), "+v"(yq));
                    asm("v_permlane16_swap_b32 %0, %1" : "+v"(xq), "+v"(yq));
                    v[rr]     = xq;
                    v[4 + rr] = yq;
                }
                split8(v, nh[t][kb], nl[t][kb]);
            }
        }
        const int base_h = layer ? 12288 : 4096;
        const int base_l = layer ? 16384 : 8192;
        const float* __restrict__ bias = layer ? b3 : b2;
        #pragma unroll
        for (int nb = 0; nb < 4; ++nb) {
            const f32x4 bv = *(const f32x4*)(bias + nb * 16 + quad * 4);
            f32x4 c[2];
            #pragma unroll
            for (int t = 0; t < 2; ++t) c[t] = bv;
            #pragma unroll
            for (int kb = 0; kb < 2; ++kb) {
                const int idx = ((kb * 4 + nb) * 64 + lane) * 8;
                const bf16x8 wh = *(const bf16x8*)(wb + base_h + idx);
                const bf16x8 wl = *(const bf16x8*)(wb + base_l + idx);
                #pragma unroll
                for (int t = 0; t < 2; ++t) {
                    c[t] = __builtin_amdgcn_mfma_f32_16x16x32_bf16(wh, nl[t][kb], c[t], 0, 0, 0);
                    c[t] = __builtin_amdgcn_mfma_f32_16x16x32_bf16(wl, nh[t][kb], c[t], 0, 0, 0);
                    c[t] = __builtin_amdgcn_mfma_f32_16x16x32_bf16(wh, nh[t][kb], c[t], 0, 0, 0);
                }
            }
            #pragma unroll
            for (int t = 0; t < 2; ++t) acc[t][nb] = c[t];
        }
    }

    float part[2];
    #pragma unroll
    for (int t = 0; t < 2; ++t) {
        float s = 0.f;
        #pragma unroll
        for (int nb = 0; nb < 4; ++nb) {
            const f32x4 wo4 = *(const f32x4*)(Wo + nb * 16 + quad * 4);
            #pragma unroll
            for (int r = 0; r < 4; ++r)
                s = fmaf(fmaxf(acc[t][nb][r], 0.f), wo4[r], s);
        }
        part[t] = s;
    }
    #pragma unroll
    for (int t = 0; t < 2; ++t) {
        part[t] += __shfl_xor(part[t], 16, 64);
        part[t] += __shfl_xor(part[t], 32, 64);
    }
    if (quad == 0) {
        const float b = bo[0];
        #pragma unroll
        for (int t = 0; t < 2; ++t) {
            const int po = p0 + t * 16 + l15;
            if (po < n) out[po] = part[t] + b;
        }
    }
}

// ---------------- fp32 MLP (ws-fallback path) ----------------
__global__ __launch_bounds__(256, 3)
void mlp_forward(const u32x2* __restrict__ featT,
                 const float* __restrict__ W1, const float* __restrict__ b1,
                 const float* __restrict__ W2, const float* __restrict__ b2,
                 const float* __restrict__ W3, const float* __restrict__ b3,
                 const float* __restrict__ Wo, const float* __restrict__ bo,
                 float* __restrict__ out, int n)
{
    const int p = blockIdx.x * 256 + threadIdx.x;
    if (p >= n) return;
    const v2f z2 = {0.f, 0.f};
    v2f A[32], B[32];
    #pragma unroll
    for (int jq = 0; jq < 16; ++jq) {
        const v4f b = *(const v4f*)(b1 + 4 * jq);
        A[2 * jq] = b.xy; A[2 * jq + 1] = b.zw;
    }
    #pragma unroll
    for (int l = 0; l < 16; ++l) {
        const u32x2 e = __builtin_nontemporal_load(&featT[(size_t)l * n + p]);
        union { u32 u; float f; } h0, h1, l0, l1;
        h0.u = e.x << 16; h1.u = e.x & 0xffff0000u;
        l0.u = e.y << 16; l1.u = e.y & 0xffff0000u;
        v2f f; f.x = h0.f + l0.f; f.y = h1.f + l1.f;
        const v4f* w0 = (const v4f*)(W1 + (size_t)(2 * l) * 64);
        const v4f* w1 = (const v4f*)(W1 + (size_t)(2 * l + 1) * 64);
        const v2f hh0 = {f.x, f.x}, hh1 = {f.y, f.y};
        #pragma unroll
        for (int jq = 0; jq < 16; ++jq) {
            const v4f wa = w0[jq];
            A[2 * jq]     = __builtin_elementwise_fma(hh0, wa.xy, A[2 * jq]);
            A[2 * jq + 1] = __builtin_elementwise_fma(hh0, wa.zw, A[2 * jq + 1]);
        }
        #pragma unroll
        for (int jq = 0; jq < 16; ++jq) {
            const v4f wb2 = w1[jq];
            A[2 * jq]     = __builtin_elementwise_fma(hh1, wb2.xy, A[2 * jq]);
            A[2 * jq + 1] = __builtin_elementwise_fma(hh1, wb2.zw, A[2 * jq + 1]);
        }
    }
    #pragma unroll
    for (int j = 0; j < 32; ++j) A[j] = __builtin_elementwise_max(A[j], z2);
    #pragma unroll
    for (int jq = 0; jq < 16; ++jq) {
        const v4f b = *(const v4f*)(b2 + 4 * jq);
        B[2 * jq] = b.xy; B[2 * jq + 1] = b.zw;
    }
    #pragma unroll
    for (int k = 0; k < 64; ++k) {
        const float hv = A[k >> 1][k & 1];
        const v2f h = {hv, hv};
        const v4f* w = (const v4f*)(W2 + (size_t)k * 64);
        #pragma unroll
        for (int jq = 0; jq < 16; ++jq) {
            const v4f wa = w[jq];
            B[2 * jq]     = __builtin_elementwise_fma(h, wa.xy, B[2 * jq]);
            B[2 * jq + 1] = __builtin_elementwise_fma(h, wa.zw, B[2 * jq + 1]);
        }
    }
    #pragma unroll
    for (int j = 0; j < 32; ++j) B[j] = __builtin_elementwise_max(B[j], z2);
    #pragma unroll
    for (int jq = 0; jq < 16; ++jq) {
        const v4f b = *(const v4f*)(b3 + 4 * jq);
        A[2 * jq] = b.xy; A[2 * jq + 1] = b.zw;
    }
    #pragma unroll
    for (int k = 0; k < 64; ++k) {
        const float hv = B[k >> 1][k & 1];
        const v2f h = {hv, hv};
        const v4f* w = (const v4f*)(W3 + (size_t)k * 64);
        #pragma unroll
        for (int jq = 0; jq < 16; ++jq) {
            const v4f wa = w[jq];
            A[2 * jq]     = __builtin_elementwise_fma(h, wa.xy, A[2 * jq]);
            A[2 * jq + 1] = __builtin_elementwise_fma(h, wa.zw, A[2 * jq + 1]);
        }
    }
    v2f o2 = z2;
    #pragma unroll
    for (int jq = 0; jq < 16; ++jq) {
        const v4f wa = *(const v4f*)(Wo + 4 * jq);
        o2 = __builtin_elementwise_fma(__builtin_elementwise_max(A[2 * jq], z2),     wa.xy, o2);
        o2 = __builtin_elementwise_fma(__builtin_elementwise_max(A[2 * jq + 1], z2), wa.zw, o2);
    }
    out[p] = o2.x + o2.y + bo[0];
}

// ---------------- fallback (ws too small): R1-style fused ----------------
__global__ __launch_bounds__(256, 2)
void hashpinn_fused(const float* __restrict__ x,
                    const float* __restrict__ table,
                    const float* __restrict__ W1, const float* __restrict__ b1,
                    const float* __restrict__ W2, const float* __restrict__ b2,
                    const float* __restrict__ W3, const float* __restrict__ b3,
                    const float* __restrict__ Wo, const float* __restrict__ bo,
                    float* __restrict__ out, int n, ResArr rv)
{
    const int p = blockIdx.x * 256 + threadIdx.x;
    if (p >= n) return;
    const float px = x[3*p+0], py = x[3*p+1], pz = x[3*p+2];
    float feat[32];
    #pragma unroll
    for (int l = 0; l < 16; ++l) {
        const int res = rv.r[l];
        const float rf = (float)(res - 1);
        const float fx = px*rf, fy = py*rf, fz = pz*rf;
        int ix=(int)floorf(fx), iy=(int)floorf(fy), iz=(int)floorf(fz);
        ix=min(max(ix,0),res-2); iy=min(max(iy,0),res-2); iz=min(max(iz,0),res-2);
        const float tx=fx-(float)ix, ty=fy-(float)iy, tz=fz-(float)iz;
        const float sx=1.f-tx, sy=1.f-ty, sz=1.f-tz;
        const float2* tbl=(const float2*)table+(size_t)l*HASH_SZ;
        const bool dense=((long long)res*res*res<=(long long)HASH_SZ);
        float a0=0.f, a1=0.f;
        #pragma unroll
        for (int c=0;c<8;++c){
            const uint32_t cx=(uint32_t)(ix+((c>>2)&1));
            const uint32_t cy=(uint32_t)(iy+((c>>1)&1));
            const uint32_t cz=(uint32_t)(iz+(c&1));
            uint32_t idx = dense ? cx+(uint32_t)res*(cy+(uint32_t)res*cz)
                                 : ((cx*1u ^ cy*PR2 ^ cz*PR3)&HMASK);
            const float2 v=tbl[idx];
            const float w=(((c>>2)&1)?tx:sx)*(((c>>1)&1)?ty:sy)*((c&1)?tz:sz);
            a0=fmaf(w,v.x,a0); a1=fmaf(w,v.y,a1);
        }
        feat[2*l]=a0; feat[2*l+1]=a1;
    }
    float A[64], B[64];
    #pragma unroll
    for (int j=0;j<64;++j) A[j]=b1[j];
    #pragma unroll
    for (int k=0;k<32;++k){ const float h=feat[k];
        #pragma unroll
        for (int j=0;j<64;++j) A[j]=fmaf(h,W1[k*64+j],A[j]); }
    #pragma unroll 1
    for (int it=0;it<2;++it){
        const float* W = it?W3:W2; const float* bb = it?b3:b2;
        #pragma unroll
        for (int j=0;j<64;++j){ A[j]=fmaxf(A[j],0.f); B[j]=bb[j]; }
        #pragma unroll
        for (int k=0;k<64;++k){ const float h=A[k];
            #pragma unroll
            for (int j=0;j<64;++j) B[j]=fmaf(h,W[k*64+j],B[j]); }
        #pragma unroll
        for (int j=0;j<64;++j) A[j]=B[j];
    }
    float o=bo[0];
    #pragma unroll
    for (int j=0;j<64;++j) o=fmaf(fmaxf(A[j],0.f),Wo[j],o);
    out[p]=o;
}

static inline void launch_encode(int nlev, const float* x, const float* table,
                                 u32x2* featT, int n, int lb, const ResArr& rv,
                                 hipStream_t stream) {
    const dim3 g(4096), b(256);
    switch (nlev) {
        case 1: hipLaunchKernelGGL(encode_k<1>, g, b, 0, stream, x, table, featT, n, lb, rv); break;
        case 2: hipLaunchKernelGGL(encode_k<2>, g, b, 0, stream, x, table, featT, n, lb, rv); break;
        case 3: hipLaunchKernelGGL(encode_k<3>, g, b, 0, stream, x, table, featT, n, lb, rv); break;
        case 4: hipLaunchKernelGGL(encode_k<4>, g, b, 0, stream, x, table, featT, n, lb, rv); break;
        case 5: hipLaunchKernelGGL(encode_k<5>, g, b, 0, stream, x, table, featT, n, lb, rv); break;
        case 6: hipLaunchKernelGGL(encode_k<6>, g, b, 0, stream, x, table, featT, n, lb, rv); break;
        case 7: hipLaunchKernelGGL(encode_k<7>, g, b, 0, stream, x, table, featT, n, lb, rv); break;
        default: hipLaunchKernelGGL(encode_k<8>, g, b, 0, stream, x, table, featT, n, lb, rv); break;
    }
}

extern "C" void kernel_launch(void* const* d_in, const int* in_sizes, int n_in,
                              void* d_out, int out_size, void* d_ws, size_t ws_size,
                              hipStream_t stream) {
    const float* x     = (const float*)d_in[0];
    const float* table = (const float*)d_in[1];
    const float* W1    = (const float*)d_in[2];
    const float* b1    = (const float*)d_in[3];
    const float* W2    = (const float*)d_in[4];
    const float* b2    = (const float*)d_in[5];
    const float* W3    = (const float*)d_in[6];
    const float* b3    = (const float*)d_in[7];
    const float* Wo    = (const float*)d_in[8];
    const float* bo    = (const float*)d_in[9];
    float* out = (float*)d_out;

    const int n = in_sizes[0] / 3;

    ResArr rv;
    const double scale = std::exp2(std::log2(2048.0 / 16.0) / 15.0);
    for (int l = 0; l < 16; ++l)
        rv.r[l] = (int)std::ceil(16.0 * std::pow(scale, (double)l));

    int dense_end = 0;
    while (dense_end < 16) {
        long long r = rv.r[dense_end];
        if (r * r * r <= (long long)HASH_SZ) ++dense_end; else break;
    }
    if (dense_end > 8) dense_end = 8;

    const size_t wb_bytes = 20480 * sizeof(unsigned short);
    const size_t tab16_bytes = (size_t)16 * HASH_SZ * sizeof(u32);
    const int total_entries = 16 * (int)HASH_SZ;

    // ---- two-half fused fp16 path ----
    int h0 = ((n + 1) / 2 + 1) & ~1;
    if (h0 > n) h0 = n;
    const int h1 = n - h0;
    const int ns0 = (h0 + 1) & ~1;
    const int ns1 = (h1 + 1) & ~1;
    const int nsmax = ns0 > ns1 ? ns0 : ns1;
    const int nhashed = 16 - dense_end;
    const size_t feat_half_bytes = (size_t)nsmax * nhashed * sizeof(u32x2);

    const size_t feat_bytes = (size_t)n * 16 * sizeof(u32x2);   // full (fallbacks)

    if (ws_size >= feat_half_bytes + wb_bytes + tab16_bytes) {
        u32x2* featT = (u32x2*)d_ws;
        unsigned short* wb = (unsigned short*)((char*)d_ws + feat_half_bytes);
        u32* tab16 = (u32*)((char*)d_ws + feat_half_bytes + wb_bytes);

        hipLaunchKernelGGL(prep_weights, dim3(1), dim3(256), 0, stream, W1, W2, W3, wb);
        hipLaunchKernelGGL(cvt_table, dim3(8192), dim3(256), 0, stream,
                           table, tab16, total_entries);

        for (int half = 0; half < 2; ++half) {
            const int off = half ? h0 : 0;
            const int nh  = half ? h1 : h0;
            const int ns  = half ? ns1 : ns0;
            if (nh <= 0) continue;
            const float* xh = x + (size_t)3 * off;
            const dim3 ge((nh + 511) / 512), be(256);

            for (int l = dense_end; l < 16; ++l)
                hipLaunchKernelGGL(encode16h_k, ge, be, 0, stream,
                                   xh, tab16 + (size_t)l * HASH_SZ, featT,
                                   nh, ns, l - dense_end, rv.r[l]);

            const int nblocks = (nh + 127) / 128;   // 128 pts/block (4 waves x 32)
            hipLaunchKernelGGL(mlp_mfma_f, dim3(nblocks), dim3(256), 0, stream,
                               featT, wb, b1, b2, b3, Wo, bo, out + off, nh, ns,
                               xh, tab16, rv, dense_end);
        }
    } else if (ws_size >= feat_bytes + wb_bytes) {
        // ---- fallback: full fp32-split featT + non-fused MFMA mlp (R12 path) ----
        u32x2* featT = (u32x2*)d_ws;
        unsigned short* wb = (unsigned short*)((char*)d_ws + feat_bytes);

        hipLaunchKernelGGL(prep_weights, dim3(1), dim3(256), 0, stream, W1, W2, W3, wb);

        if (dense_end > 0)
            launch_encode(dense_end, x, table, featT, n, 0, rv, stream);
        for (int l = dense_end; l < 16; ++l)
            launch_encode(1, x, table, featT, n, l, rv, stream);

        const int nblocks = (n + 127) / 128;
        hipLaunchKernelGGL(mlp_mfma, dim3(nblocks), dim3(256), 0, stream,
                           featT, wb, b1, b2, b3, Wo, bo, out, n, n);
    } else if (ws_size >= feat_bytes) {
        u32x2* featT = (u32x2*)d_ws;
        if (dense_end > 0)
            launch_encode(dense_end, x, table, featT, n, 0, rv, stream);
        for (int l = dense_end; l < 16; ++l)
            launch_encode(1, x, table, featT, n, l, rv, stream);
        hipLaunchKernelGGL(mlp_forward, dim3((n + 255) / 256), dim3(256), 0, stream,
                           featT, W1, b1, W2, b2, W3, b3, Wo, bo, out, n);
    } else {
        hipLaunchKernelGGL(hashpinn_fused, dim3((n + 255) / 256), dim3(256), 0, stream,
                           x, table, W1, b1, W2, b2, W3, b3, Wo, bo, out, n, rv);
    }
}

// Round 8
// 966.576 us; speedup vs baseline: 1.1343x; 1.1343x over previous
//
#include <hip/hip_runtime.h>
#include <hip/hip_fp16.h>
#include <cmath>
#include <cstdint>

// HashPINN R17:
//  - R16 post-mortem: __float2bfloat16-based split8 FAILED correctness
//    (absmax 1.38e-5, structural scale) -> the HIP bf16 cast path is not a
//    trustworthy RNE convert here. split8 reverted to the R12-proven manual
//    bit-twiddle. Anchor: R14 = 982us, absmax 2.384186e-07.
//  - R17 pipelines the two independent resources: hashed encode is
//    MSHR/latency-bound (VALU+MFMA idle), MLP is VALU/MFMA-bound (miss
//    queue idle). Points split into 4 QUARTERS with TWO featT slabs
//    (2x64MB + wb + tab16(32MB) = 160MB, same footprint R14 proved fits).
//    Fused dispatch i: every 4th block runs the R14 MLP for quarter i-1
//    (reads slab P), other blocks run the 16 per-level encode segments for
//    quarter i (writes slab C). Block-uniform partition -> no divergence
//    (R15's error was per-LANE fusion). No data hazard (distinct slabs).
//    Also collapses ~48 dispatch ramps to 7.
//  - All math bit-identical to R14 -> absmax must be exactly 2.384186e-07.

#define HASH_SZ (1u << 19)
#define HMASK   (HASH_SZ - 1u)
#define PR2 2654435761u
#define PR3 805459861u

typedef float v2f __attribute__((ext_vector_type(2)));
typedef float v4f __attribute__((ext_vector_type(4)));
typedef v4f v4fu __attribute__((aligned(8)));
typedef v2f v2fu __attribute__((aligned(8)));
typedef short bf16x8 __attribute__((ext_vector_type(8)));
typedef float f32x4 __attribute__((ext_vector_type(4)));
typedef unsigned int u32;
typedef u32 u32x2 __attribute__((ext_vector_type(2)));
typedef u32 u32x4 __attribute__((ext_vector_type(4)));
typedef u32x4 u32x4u __attribute__((aligned(8)));

struct ResArr { int r[16]; };

// ---------- bf16 helpers (R12-proven manual forms) ----------
__device__ __forceinline__ unsigned short bf16_rne(float f) {
    union { float f; unsigned u; } v; v.f = f;
    unsigned u = v.u;
    unsigned r = (u + 0x7fffu + ((u >> 16) & 1u)) >> 16;
    return (unsigned short)r;
}
__device__ __forceinline__ float bf16f(unsigned short h) {
    union { unsigned u; float f; } v; v.u = ((unsigned)h) << 16;
    return v.f;
}
// hi = TRUNCATED bf16 (cheap); lo = RNE bf16 of the exact remainder.
__device__ __forceinline__ void split8(const float* x, bf16x8& hi, bf16x8& lo) {
    #pragma unroll
    for (int j = 0; j < 8; ++j) {
        union { float f; unsigned u; } v; v.f = x[j];
        const unsigned hu = v.u & 0xffff0000u;
        hi[j] = (short)(hu >> 16);
        union { unsigned u; float f; } hf; hf.u = hu;
        const float d = x[j] - hf.f;
        union { float f; unsigned u; } dv; dv.f = d;
        lo[j] = (short)((dv.u + 0x7fffu + ((dv.u >> 16) & 1u)) >> 16);
    }
}
__device__ __forceinline__ u32 rne16u(float f) {
    union { float f; u32 u; } v; v.f = f;
    return (v.u + 0x7fffu + ((v.u >> 16) & 1u)) >> 16;
}
// pack two features into {hi0|hi1<<16, lo0|lo1<<16} (bit-identical to split8)
__device__ __forceinline__ u32x2 pack_split2(float f0, float f1) {
    union { float f; u32 u; } a, b; a.f = f0; b.f = f1;
    const u32 h0 = a.u & 0xffff0000u, h1 = b.u & 0xffff0000u;
    union { u32 u; float f; } ha, hb; ha.u = h0; hb.u = h1;
    u32x2 r;
    r.x = (h0 >> 16) | h1;
    r.y = rne16u(f0 - ha.f) | (rne16u(f1 - hb.f) << 16);
    return r;
}

// ---------- fp16 helpers ----------
__device__ __forceinline__ u32 pkh(float f0, float f1) {
    const __half h0 = __float2half_rn(f0), h1 = __float2half_rn(f1);
    return (u32)__half_as_ushort(h0) | ((u32)__half_as_ushort(h1) << 16);
}
__device__ __forceinline__ v2f cvt2(u32 e) {
    __half2 h;
    *reinterpret_cast<u32*>(&h) = e;
    v2f r; r.x = __low2float(h); r.y = __high2float(h);
    return r;
}
// select entry k (0..3) from a 16B window without runtime vector indexing
__device__ __forceinline__ u32 sel4(u32x4 P, u32 k) {
    const u32 a = (k & 1u) ? P.y : P.x;
    const u32 b = (k & 1u) ? P.w : P.z;
    return (k & 2u) ? b : a;
}

// ---------------- table conversion: fp32 pairs -> packed fp16 ----------------
__global__ __launch_bounds__(256, 8)
void cvt_table(const float* __restrict__ table, u32* __restrict__ tab16, int total)
{
    const int e0 = (blockIdx.x * 256 + threadIdx.x) * 4;
    if (e0 >= total) return;
    const v4f a = __builtin_nontemporal_load((const v4f*)(table + 2 * (size_t)e0));
    const v4f b = __builtin_nontemporal_load((const v4f*)(table + 2 * (size_t)e0 + 4));
    u32x4 o;
    o.x = pkh(a.x, a.y); o.y = pkh(a.z, a.w);
    o.z = pkh(b.x, b.y); o.w = pkh(b.z, b.w);
    *(u32x4*)(tab16 + e0) = o;
}

// ---------------- fp16-table gather (16B windows, R14-proven) ----------------
__device__ __forceinline__ void gather16_one(
    const u32* __restrict__ tab, int res, bool dense,
    float px, float py, float pz, float& A0, float& A1)
{
    const float rf = (float)(res - 1);
    const float fx = px * rf, fy = py * rf, fz = pz * rf;
    int ix = (int)floorf(fx), iy = (int)floorf(fy), iz = (int)floorf(fz);
    ix = min(max(ix, 0), res - 2);
    iy = min(max(iy, 0), res - 2);
    iz = min(max(iz, 0), res - 2);
    const float tx = fx - (float)ix, ty = fy - (float)iy, tz = fz - (float)iz;
    const float sx = 1.f - tx, sy = 1.f - ty, sz = 1.f - tz;
    float a0 = 0.f, a1 = 0.f;

    if (dense) {
        const int b0 = ix + res * (iy + res * iz);
        #pragma unroll
        for (int c = 0; c < 4; ++c) {
            const int dy = c >> 1, dz = c & 1;
            const u32 idx0 = (u32)(b0 + res * dy + res * res * dz);
            const u32x4u Pv = *(const u32x4u*)(tab + (idx0 & ~1u));
            const bool hi = (idx0 & 1u) != 0u;
            const u32 e0 = hi ? Pv.y : Pv.x;
            const u32 e1 = hi ? Pv.z : Pv.y;
            const float wyz = (dy ? ty : sy) * (dz ? tz : sz);
            const float w0 = sx * wyz, w1 = tx * wyz;
            const v2f f0 = cvt2(e0), f1 = cvt2(e1);
            a0 = fmaf(w0, f0.x, a0); a1 = fmaf(w0, f0.y, a1);
            a0 = fmaf(w1, f1.x, a0); a1 = fmaf(w1, f1.y, a1);
        }
    } else {
        u32 i1a[4], k0[4];
        u32x4 P[4];
        #pragma unroll
        for (int c = 0; c < 4; ++c) {
            const int dy = c >> 1, dz = c & 1;
            const u32 r = (u32)(iy + dy) * PR2 ^ (u32)(iz + dz) * PR3;
            const u32 i0 = ((u32)ix ^ r) & HMASK;
            i1a[c] = ((u32)(ix + 1) ^ r) & HMASK;
            k0[c] = i0 & 3u;
            P[c] = *(const u32x4*)(tab + (i0 & ~3u));
        }
        const bool extra = ((ix & 3) == 3);   // (ix^(ix+1)) spans the 4-window
        u32 O[4];
        if (extra) {
            #pragma unroll
            for (int c = 0; c < 4; ++c) O[c] = tab[i1a[c]];
        } else {
            #pragma unroll
            for (int c = 0; c < 4; ++c) O[c] = 0u;
        }
        #pragma unroll
        for (int c = 0; c < 4; ++c) {
            const int dy = c >> 1, dz = c & 1;
            const u32 e0 = sel4(P[c], k0[c]);
            const u32 e1w = sel4(P[c], i1a[c] & 3u);
            const u32 e1 = extra ? O[c] : e1w;
            const float wyz = (dy ? ty : sy) * (dz ? tz : sz);
            const float w0 = sx * wyz, w1 = tx * wyz;
            const v2f f0 = cvt2(e0), f1 = cvt2(e1);
            a0 = fmaf(w0, f0.x, a0); a1 = fmaf(w0, f0.y, a1);
            a0 = fmaf(w1, f1.x, a0); a1 = fmaf(w1, f1.y, a1);
        }
    }
    A0 = a0; A1 = a1;
}

// ---------------- weight prep (layout doubles as A-operand frags) ----------------
__global__ void prep_weights(const float* __restrict__ W1,
                             const float* __restrict__ W2,
                             const float* __restrict__ W3,
                             unsigned short* __restrict__ wb)
{
    const int tid = threadIdx.x;
    const int nb = tid >> 6, lane = tid & 63;
    const int l15 = lane & 15, q = lane >> 4;
    #pragma unroll
    for (int j = 0; j < 8; ++j) {
        const float v = W1[(q * 8 + j) * 64 + nb * 16 + l15];
        const unsigned short h = bf16_rne(v);
        wb[(nb * 64 + lane) * 8 + j] = h;
        wb[2048 + (nb * 64 + lane) * 8 + j] = bf16_rne(v - bf16f(h));
    }
    #pragma unroll
    for (int kb = 0; kb < 2; ++kb) {
        #pragma unroll
        for (int j = 0; j < 8; ++j) {
            const int row = kb * 32 + q * 8 + j;
            const int idx = ((kb * 4 + nb) * 64 + lane) * 8 + j;
            float v = W2[row * 64 + nb * 16 + l15];
            unsigned short h = bf16_rne(v);
            wb[4096 + idx] = h;
            wb[8192 + idx] = bf16_rne(v - bf16f(h));
            v = W3[row * 64 + nb * 16 + l15];
            h = bf16_rne(v);
            wb[12288 + idx] = h;
            wb[16384 + idx] = bf16_rne(v - bf16f(h));
        }
    }
}

// ---------------- MLP block body (R14-proven, weights=A / acts=B, permlane) ----------------
__device__ __forceinline__ void mlp_block(
    const u32x2* __restrict__ featT,
    const unsigned short* __restrict__ wb,
    const float* __restrict__ b1, const float* __restrict__ b2,
    const float* __restrict__ b3,
    const float* __restrict__ Wo, const float* __restrict__ bo,
    float* __restrict__ out, int n, int ns, int mb)
{
    const int wave = threadIdx.x >> 6;
    const int lane = threadIdx.x & 63;
    const int l15 = lane & 15, quad = lane >> 4;
    const int p0 = (mb * 4 + wave) * 32;
    if (p0 >= n) return;

    // ---- layer 1: B-frags straight from pre-split featT ----
    bf16x8 bh[2], bl[2];
    #pragma unroll
    for (int t = 0; t < 2; ++t) {
        const int p = p0 + t * 16 + l15;
        const int pl = (p < n) ? p : (n - 1);
        u32x4 hw, lw;
        #pragma unroll
        for (int jj = 0; jj < 4; ++jj) {
            const u32x2 v = featT[(size_t)(quad * 4 + jj) * ns + pl];
            hw[jj] = v.x; lw[jj] = v.y;
        }
        bh[t] = *(bf16x8*)&hw;
        bl[t] = *(bf16x8*)&lw;
    }

    f32x4 acc[2][4];
    #pragma unroll
    for (int nb = 0; nb < 4; ++nb) {
        const bf16x8 wh = *(const bf16x8*)(wb + (nb * 64 + lane) * 8);
        const bf16x8 wl = *(const bf16x8*)(wb + 2048 + (nb * 64 + lane) * 8);
        const f32x4 bv = *(const f32x4*)(b1 + nb * 16 + quad * 4);
        #pragma unroll
        for (int t = 0; t < 2; ++t) {
            f32x4 c = bv;
            c = __builtin_amdgcn_mfma_f32_16x16x32_bf16(wh, bl[t], c, 0, 0, 0);
            c = __builtin_amdgcn_mfma_f32_16x16x32_bf16(wl, bh[t], c, 0, 0, 0);
            c = __builtin_amdgcn_mfma_f32_16x16x32_bf16(wh, bh[t], c, 0, 0, 0);
            acc[t][nb] = c;
        }
    }

    // ---- hidden layers 2 & 3 (permlane exchange, verified R12) ----
    #pragma unroll
    for (int layer = 0; layer < 2; ++layer) {
        bf16x8 nh[2][2], nl[2][2];
        #pragma unroll
        for (int t = 0; t < 2; ++t) {
            #pragma unroll
            for (int kb = 0; kb < 2; ++kb) {
                float v[8];
                #pragma unroll
                for (int rr = 0; rr < 4; ++rr) {
                    float xq = fmaxf(acc[t][2 * kb][rr],     0.f);
                    float yq = fmaxf(acc[t][2 * kb + 1][rr], 0.f);
                    asm("v_permlane32_swap_b32 %0, %1" : "+v"(xq), "+v"(yq));
                    asm("v_permlane16_swap_b32 %0, %1" : "+v"(xq), "+v"(yq));
                    v[rr]     = xq;   // k = quad*8 + rr
                    v[4 + rr] = yq;   // k = quad*8 + 4 + rr
                }
                split8(v, nh[t][kb], nl[t][kb]);
            }
        }
        const int base_h = layer ? 12288 : 4096;
        const int base_l = layer ? 16384 : 8192;
        const float* __restrict__ bias = layer ? b3 : b2;
        #pragma unroll
        for (int nb = 0; nb < 4; ++nb) {
            const f32x4 bv = *(const f32x4*)(bias + nb * 16 + quad * 4);
            f32x4 c[2];
            #pragma unroll
            for (int t = 0; t < 2; ++t) c[t] = bv;
            #pragma unroll
            for (int kb = 0; kb < 2; ++kb) {
                const int idx = ((kb * 4 + nb) * 64 + lane) * 8;
                const bf16x8 wh = *(const bf16x8*)(wb + base_h + idx);
                const bf16x8 wl = *(const bf16x8*)(wb + base_l + idx);
                #pragma unroll
                for (int t = 0; t < 2; ++t) {
                    c[t] = __builtin_amdgcn_mfma_f32_16x16x32_bf16(wh, nl[t][kb], c[t], 0, 0, 0);
                    c[t] = __builtin_amdgcn_mfma_f32_16x16x32_bf16(wl, nh[t][kb], c[t], 0, 0, 0);
                    c[t] = __builtin_amdgcn_mfma_f32_16x16x32_bf16(wh, nh[t][kb], c[t], 0, 0, 0);
                }
            }
            #pragma unroll
            for (int t = 0; t < 2; ++t) acc[t][nb] = c[t];
        }
    }

    // ---- output layer: lane holds 16 neurons of point l15; quad-reduce ----
    float part[2];
    #pragma unroll
    for (int t = 0; t < 2; ++t) {
        float s = 0.f;
        #pragma unroll
        for (int nb = 0; nb < 4; ++nb) {
            const f32x4 wo4 = *(const f32x4*)(Wo + nb * 16 + quad * 4);
            #pragma unroll
            for (int r = 0; r < 4; ++r)
                s = fmaf(fmaxf(acc[t][nb][r], 0.f), wo4[r], s);
        }
        part[t] = s;
    }
    #pragma unroll
    for (int t = 0; t < 2; ++t) {
        part[t] += __shfl_xor(part[t], 16, 64);
        part[t] += __shfl_xor(part[t], 32, 64);
    }
    if (quad == 0) {
        const float b = bo[0];
        #pragma unroll
        for (int t = 0; t < 2; ++t) {
            const int po = p0 + t * 16 + l15;
            if (po < n) out[po] = part[t] + b;
        }
    }
}

__global__ __launch_bounds__(256, 4)
void mlp_mfma(const u32x2* __restrict__ featT,
              const unsigned short* __restrict__ wb,
              const float* __restrict__ b1, const float* __restrict__ b2,
              const float* __restrict__ b3,
              const float* __restrict__ Wo, const float* __restrict__ bo,
              float* __restrict__ out, int n, int ns)
{
    mlp_block(featT, wb, b1, b2, b3, Wo, bo, out, n, ns, blockIdx.x);
}

// ---------------- fused dispatch: encode quarter i  ||  MLP quarter i-1 ----------------
// Block-uniform partition: if ilv, every 4th block (b&3==3, b>>2<M) is an MLP
// block; else first M blocks are MLP. Remaining blocks form 16 encode
// segments of bpl blocks each (level = eb/bpl). Encode writes slab fe;
// MLP reads slab fm (distinct) -> no intra-dispatch hazard.
__global__ __launch_bounds__(256, 4)
void fused_q(const float* __restrict__ xe, const u32* __restrict__ tab16,
             u32x2* __restrict__ fe, int ne, int nse,
             const u32x2* __restrict__ fm,
             const unsigned short* __restrict__ wb,
             const float* __restrict__ b1, const float* __restrict__ b2,
             const float* __restrict__ b3,
             const float* __restrict__ Wo, const float* __restrict__ bo,
             float* __restrict__ outm, int nm, int nsm,
             ResArr rv, int de, int bpl, int M, int ilv)
{
    const int b = blockIdx.x;
    int eb;
    if (ilv) {
        const int q4 = b >> 2, r4 = b & 3;
        if (r4 == 3 && q4 < M) {
            mlp_block(fm, wb, b1, b2, b3, Wo, bo, outm, nm, nsm, q4);
            return;
        }
        eb = b - ((r4 == 3) ? M : min(q4, M));
    } else {
        if (b < M) {
            mlp_block(fm, wb, b1, b2, b3, Wo, bo, outm, nm, nsm, b);
            return;
        }
        eb = b - M;
    }
    const int lvl = eb / bpl;
    if (lvl >= 16) return;
    const int lblk = eb - lvl * bpl;
    const int res = rv.r[lvl];
    const bool dense = (lvl < de);
    const u32* tbl = tab16 + (size_t)lvl * HASH_SZ;

    const int nth2 = bpl * 512;
    for (int q = (lblk * 256 + (int)threadIdx.x) * 2; q < ne; q += nth2) {
        float p0x, p0y, p0z, p1x, p1y, p1z;
        const bool two = (q + 1 < ne);
        if (two) {
            const v4fu a = __builtin_nontemporal_load((const v4fu*)(xe + 3 * q));
            const v2f  bb = __builtin_nontemporal_load((const v2fu*)(xe + 3 * q + 4));
            p0x = a.x; p0y = a.y; p0z = a.z; p1x = a.w; p1y = bb.x; p1z = bb.y;
        } else {
            p0x = xe[3 * q]; p0y = xe[3 * q + 1]; p0z = xe[3 * q + 2];
            p1x = p0x; p1y = p0y; p1z = p0z;
        }
        float a00, a01, a10, a11;
        gather16_one(tbl, res, dense, p0x, p0y, p0z, a00, a01);
        gather16_one(tbl, res, dense, p1x, p1y, p1z, a10, a11);
        if (two) {
            const u32x2 e0 = pack_split2(a00, a01);
            const u32x2 e1 = pack_split2(a10, a11);
            u32x4 st; st.x = e0.x; st.y = e0.y; st.z = e1.x; st.w = e1.y;
            __builtin_nontemporal_store(st, (u32x4*)&fe[(size_t)lvl * nse + q]);
        } else {
            __builtin_nontemporal_store(pack_split2(a00, a01),
                                        &fe[(size_t)lvl * nse + q]);
        }
    }
}

// ---------------- fp32 encode (ws-fallback path) ----------------
__device__ __forceinline__ void gather_one(
    const v2f* __restrict__ tbl, int res, bool dense,
    float px, float py, float pz, float& A0, float& A1)
{
    const float rf = (float)(res - 1);
    const float fx = px * rf, fy = py * rf, fz = pz * rf;
    int ix = (int)floorf(fx), iy = (int)floorf(fy), iz = (int)floorf(fz);
    ix = min(max(ix, 0), res - 2);
    iy = min(max(iy, 0), res - 2);
    iz = min(max(iz, 0), res - 2);
    const float tx = fx - (float)ix, ty = fy - (float)iy, tz = fz - (float)iz;
    const float sx = 1.f - tx, sy = 1.f - ty, sz = 1.f - tz;
    float a0 = 0.f, a1 = 0.f;

    if (dense) {
        const int b0 = ix + res * (iy + res * iz);
        v4fu P[4];
        #pragma unroll
        for (int c = 0; c < 4; ++c) {
            const int dy = c >> 1, dz = c & 1;
            P[c] = *(const v4fu*)((const float*)tbl + 2 * (b0 + res * dy + res * res * dz));
        }
        #pragma unroll
        for (int c = 0; c < 4; ++c) {
            const int dy = c >> 1, dz = c & 1;
            const float wyz = (dy ? ty : sy) * (dz ? tz : sz);
            const float w0 = sx * wyz, w1 = tx * wyz;
            a0 = fmaf(w0, P[c].x, a0); a1 = fmaf(w0, P[c].y, a1);
            a0 = fmaf(w1, P[c].z, a0); a1 = fmaf(w1, P[c].w, a1);
        }
    } else {
        uint32_t i0[4], i1[4];
        v4f P[4];
        #pragma unroll
        for (int c = 0; c < 4; ++c) {
            const int dy = c >> 1, dz = c & 1;
            const uint32_t r = (uint32_t)(iy + dy) * PR2 ^ (uint32_t)(iz + dz) * PR3;
            i0[c] = ((uint32_t)ix ^ r) & HMASK;
            i1[c] = ((uint32_t)(ix + 1) ^ r) & HMASK;
            P[c] = *(const v4f*)((const float*)tbl + 2 * (i0[c] & ~1u));
        }
        const bool odd = (ix & 1);
        v2f O[4];
        if (odd) {
            #pragma unroll
            for (int c = 0; c < 4; ++c) O[c] = tbl[i1[c]];
        } else {
            #pragma unroll
            for (int c = 0; c < 4; ++c) { v2f z = {0.f, 0.f}; O[c] = z; }
        }
        #pragma unroll
        for (int c = 0; c < 4; ++c) {
            const int dy = c >> 1, dz = c & 1;
            const bool hi = (i0[c] & 1);
            v2f c0, e;
            c0.x = hi ? P[c].z : P[c].x;  c0.y = hi ? P[c].w : P[c].y;
            e.x  = hi ? P[c].x : P[c].z;  e.y  = hi ? P[c].y : P[c].w;
            const v2f c1 = odd ? O[c] : e;
            const float wyz = (dy ? ty : sy) * (dz ? tz : sz);
            const float w0 = sx * wyz, w1 = tx * wyz;
            a0 = fmaf(w0, c0.x, a0); a1 = fmaf(w0, c0.y, a1);
            a0 = fmaf(w1, c1.x, a0); a1 = fmaf(w1, c1.y, a1);
        }
    }
    A0 = a0; A1 = a1;
}

template<int NLEV>
__global__ __launch_bounds__(256, 8)
void encode_k(const float* __restrict__ x, const float* __restrict__ table,
              u32x2* __restrict__ featT, int n, int lb, ResArr rv)
{
    const int nth2 = gridDim.x * 512;
    for (int q = (blockIdx.x * 256 + threadIdx.x) * 2; q < n; q += nth2) {
        float p0x, p0y, p0z, p1x, p1y, p1z;
        const bool two = (q + 1 < n);
        if (two) {
            const v4fu a = __builtin_nontemporal_load((const v4fu*)(x + 3 * q));
            const v2f  b = __builtin_nontemporal_load((const v2fu*)(x + 3 * q + 4));
            p0x = a.x; p0y = a.y; p0z = a.z; p1x = a.w; p1y = b.x; p1z = b.y;
        } else {
            p0x = x[3 * q]; p0y = x[3 * q + 1]; p0z = x[3 * q + 2];
            p1x = p0x; p1y = p0y; p1z = p0z;
        }
        #pragma unroll
        for (int il = 0; il < NLEV; ++il) {
            const int l = lb + il;
            const int res = rv.r[l];
            const bool dense = ((long long)res * res * res <= (long long)HASH_SZ);
            const v2f* tbl = (const v2f*)table + (size_t)l * HASH_SZ;
            float a00, a01, a10, a11;
            gather_one(tbl, res, dense, p0x, p0y, p0z, a00, a01);
            gather_one(tbl, res, dense, p1x, p1y, p1z, a10, a11);
            if (two) {
                const u32x2 e0 = pack_split2(a00, a01);
                const u32x2 e1 = pack_split2(a10, a11);
                u32x4 st; st.x = e0.x; st.y = e0.y; st.z = e1.x; st.w = e1.y;
                __builtin_nontemporal_store(st, (u32x4*)&featT[(size_t)l * n + q]);
            } else {
                __builtin_nontemporal_store(pack_split2(a00, a01),
                                            &featT[(size_t)l * n + q]);
            }
        }
    }
}

// ---------------- fp32 MLP (ws-fallback path) ----------------
__global__ __launch_bounds__(256, 3)
void mlp_forward(const u32x2* __restrict__ featT,
                 const float* __restrict__ W1, const float* __restrict__ b1,
                 const float* __restrict__ W2, const float* __restrict__ b2,
                 const float* __restrict__ W3, const float* __restrict__ b3,
                 const float* __restrict__ Wo, const float* __restrict__ bo,
                 float* __restrict__ out, int n)
{
    const int p = blockIdx.x * 256 + threadIdx.x;
    if (p >= n) return;
    const v2f z2 = {0.f, 0.f};
    v2f A[32], B[32];
    #pragma unroll
    for (int jq = 0; jq < 16; ++jq) {
        const v4f b = *(const v4f*)(b1 + 4 * jq);
        A[2 * jq] = b.xy; A[2 * jq + 1] = b.zw;
    }
    #pragma unroll
    for (int l = 0; l < 16; ++l) {
        const u32x2 e = __builtin_nontemporal_load(&featT[(size_t)l * n + p]);
        union { u32 u; float f; } h0, h1, l0, l1;
        h0.u = e.x << 16; h1.u = e.x & 0xffff0000u;
        l0.u = e.y << 16; l1.u = e.y & 0xffff0000u;
        v2f f; f.x = h0.f + l0.f; f.y = h1.f + l1.f;
        const v4f* w0 = (const v4f*)(W1 + (size_t)(2 * l) * 64);
        const v4f* w1 = (const v4f*)(W1 + (size_t)(2 * l + 1) * 64);
        const v2f hh0 = {f.x, f.x}, hh1 = {f.y, f.y};
        #pragma unroll
        for (int jq = 0; jq < 16; ++jq) {
            const v4f wa = w0[jq];
            A[2 * jq]     = __builtin_elementwise_fma(hh0, wa.xy, A[2 * jq]);
            A[2 * jq + 1] = __builtin_elementwise_fma(hh0, wa.zw, A[2 * jq + 1]);
        }
        #pragma unroll
        for (int jq = 0; jq < 16; ++jq) {
            const v4f wb2 = w1[jq];
            A[2 * jq]     = __builtin_elementwise_fma(hh1, wb2.xy, A[2 * jq]);
            A[2 * jq + 1] = __builtin_elementwise_fma(hh1, wb2.zw, A[2 * jq + 1]);
        }
    }
    #pragma unroll
    for (int j = 0; j < 32; ++j) A[j] = __builtin_elementwise_max(A[j], z2);
    #pragma unroll
    for (int jq = 0; jq < 16; ++jq) {
        const v4f b = *(const v4f*)(b2 + 4 * jq);
        B[2 * jq] = b.xy; B[2 * jq + 1] = b.zw;
    }
    #pragma unroll
    for (int k = 0; k < 64; ++k) {
        const float hv = A[k >> 1][k & 1];
        const v2f h = {hv, hv};
        const v4f* w = (const v4f*)(W2 + (size_t)k * 64);
        #pragma unroll
        for (int jq = 0; jq < 16; ++jq) {
            const v4f wa = w[jq];
            B[2 * jq]     = __builtin_elementwise_fma(h, wa.xy, B[2 * jq]);
            B[2 * jq + 1] = __builtin_elementwise_fma(h, wa.zw, B[2 * jq + 1]);
        }
    }
    #pragma unroll
    for (int j = 0; j < 32; ++j) B[j] = __builtin_elementwise_max(B[j], z2);
    #pragma unroll
    for (int jq = 0; jq < 16; ++jq) {
        const v4f b = *(const v4f*)(b3 + 4 * jq);
        A[2 * jq] = b.xy; A[2 * jq + 1] = b.zw;
    }
    #pragma unroll
    for (int k = 0; k < 64; ++k) {
        const float hv = B[k >> 1][k & 1];
        const v2f h = {hv, hv};
        const v4f* w = (const v4f*)(W3 + (size_t)k * 64);
        #pragma unroll
        for (int jq = 0; jq < 16; ++jq) {
            const v4f wa = w[jq];
            A[2 * jq]     = __builtin_elementwise_fma(h, wa.xy, A[2 * jq]);
            A[2 * jq + 1] = __builtin_elementwise_fma(h, wa.zw, A[2 * jq + 1]);
        }
    }
    v2f o2 = z2;
    #pragma unroll
    for (int jq = 0; jq < 16; ++jq) {
        const v4f wa = *(const v4f*)(Wo + 4 * jq);
        o2 = __builtin_elementwise_fma(__builtin_elementwise_max(A[2 * jq], z2),     wa.xy, o2);
        o2 = __builtin_elementwise_fma(__builtin_elementwise_max(A[2 * jq + 1], z2), wa.zw, o2);
    }
    out[p] = o2.x + o2.y + bo[0];
}

// ---------------- fallback (ws too small): R1-style fused ----------------
__global__ __launch_bounds__(256, 2)
void hashpinn_fused(const float* __restrict__ x,
                    const float* __restrict__ table,
                    const float* __restrict__ W1, const float* __restrict__ b1,
                    const float* __restrict__ W2, const float* __restrict__ b2,
                    const float* __restrict__ W3, const float* __restrict__ b3,
                    const float* __restrict__ Wo, const float* __restrict__ bo,
                    float* __restrict__ out, int n, ResArr rv)
{
    const int p = blockIdx.x * 256 + threadIdx.x;
    if (p >= n) return;
    const float px = x[3*p+0], py = x[3*p+1], pz = x[3*p+2];
    float feat[32];
    #pragma unroll
    for (int l = 0; l < 16; ++l) {
        const int res = rv.r[l];
        const float rf = (float)(res - 1);
        const float fx = px*rf, fy = py*rf, fz = pz*rf;
        int ix=(int)floorf(fx), iy=(int)floorf(fy), iz=(int)floorf(fz);
        ix=min(max(ix,0),res-2); iy=min(max(iy,0),res-2); iz=min(max(iz,0),res-2);
        const float tx=fx-(float)ix, ty=fy-(float)iy, tz=fz-(float)iz;
        const float sx=1.f-tx, sy=1.f-ty, sz=1.f-tz;
        const float2* tbl=(const float2*)table+(size_t)l*HASH_SZ;
        const bool dense=((long long)res*res*res<=(long long)HASH_SZ);
        float a0=0.f, a1=0.f;
        #pragma unroll
        for (int c=0;c<8;++c){
            const uint32_t cx=(uint32_t)(ix+((c>>2)&1));
            const uint32_t cy=(uint32_t)(iy+((c>>1)&1));
            const uint32_t cz=(uint32_t)(iz+(c&1));
            uint32_t idx = dense ? cx+(uint32_t)res*(cy+(uint32_t)res*cz)
                                 : ((cx*1u ^ cy*PR2 ^ cz*PR3)&HMASK);
            const float2 v=tbl[idx];
            const float w=(((c>>2)&1)?tx:sx)*(((c>>1)&1)?ty:sy)*((c&1)?tz:sz);
            a0=fmaf(w,v.x,a0); a1=fmaf(w,v.y,a1);
        }
        feat[2*l]=a0; feat[2*l+1]=a1;
    }
    float A[64], B[64];
    #pragma unroll
    for (int j=0;j<64;++j) A[j]=b1[j];
    #pragma unroll
    for (int k=0;k<32;++k){ const float h=feat[k];
        #pragma unroll
        for (int j=0;j<64;++j) A[j]=fmaf(h,W1[k*64+j],A[j]); }
    #pragma unroll 1
    for (int it=0;it<2;++it){
        const float* W = it?W3:W2; const float* bb = it?b3:b2;
        #pragma unroll
        for (int j=0;j<64;++j){ A[j]=fmaxf(A[j],0.f); B[j]=bb[j]; }
        #pragma unroll
        for (int k=0;k<64;++k){ const float h=A[k];
            #pragma unroll
            for (int j=0;j<64;++j) B[j]=fmaf(h,W[k*64+j],B[j]); }
        #pragma unroll
        for (int j=0;j<64;++j) A[j]=B[j];
    }
    float o=bo[0];
    #pragma unroll
    for (int j=0;j<64;++j) o=fmaf(fmaxf(A[j],0.f),Wo[j],o);
    out[p]=o;
}

static inline void launch_encode(int nlev, const float* x, const float* table,
                                 u32x2* featT, int n, int lb, const ResArr& rv,
                                 hipStream_t stream) {
    const dim3 g(4096), b(256);
    switch (nlev) {
        case 1: hipLaunchKernelGGL(encode_k<1>, g, b, 0, stream, x, table, featT, n, lb, rv); break;
        case 2: hipLaunchKernelGGL(encode_k<2>, g, b, 0, stream, x, table, featT, n, lb, rv); break;
        case 3: hipLaunchKernelGGL(encode_k<3>, g, b, 0, stream, x, table, featT, n, lb, rv); break;
        case 4: hipLaunchKernelGGL(encode_k<4>, g, b, 0, stream, x, table, featT, n, lb, rv); break;
        case 5: hipLaunchKernelGGL(encode_k<5>, g, b, 0, stream, x, table, featT, n, lb, rv); break;
        case 6: hipLaunchKernelGGL(encode_k<6>, g, b, 0, stream, x, table, featT, n, lb, rv); break;
        case 7: hipLaunchKernelGGL(encode_k<7>, g, b, 0, stream, x, table, featT, n, lb, rv); break;
        default: hipLaunchKernelGGL(encode_k<8>, g, b, 0, stream, x, table, featT, n, lb, rv); break;
    }
}

extern "C" void kernel_launch(void* const* d_in, const int* in_sizes, int n_in,
                              void* d_out, int out_size, void* d_ws, size_t ws_size,
                              hipStream_t stream) {
    const float* x     = (const float*)d_in[0];
    const float* table = (const float*)d_in[1];
    const float* W1    = (const float*)d_in[2];
    const float* b1    = (const float*)d_in[3];
    const float* W2    = (const float*)d_in[4];
    const float* b2    = (const float*)d_in[5];
    const float* W3    = (const float*)d_in[6];
    const float* b3    = (const float*)d_in[7];
    const float* Wo    = (const float*)d_in[8];
    const float* bo    = (const float*)d_in[9];
    float* out = (float*)d_out;

    const int n = in_sizes[0] / 3;

    ResArr rv;
    const double scale = std::exp2(std::log2(2048.0 / 16.0) / 15.0);
    for (int l = 0; l < 16; ++l)
        rv.r[l] = (int)std::ceil(16.0 * std::pow(scale, (double)l));

    int dense_end = 0;
    while (dense_end < 16) {
        long long r = rv.r[dense_end];
        if (r * r * r <= (long long)HASH_SZ) ++dense_end; else break;
    }
    if (dense_end > 8) dense_end = 8;

    const size_t wb_bytes = 20480 * sizeof(unsigned short);
    const size_t tab16_bytes = (size_t)16 * HASH_SZ * sizeof(u32);
    const int total_entries = 16 * (int)HASH_SZ;

    // ---- quarter schedule ----
    const int Q = 4;
    int qoff[Q + 1];
    {
        int base = ((n + Q - 1) / Q + 1) & ~1;   // even quarter size
        for (int i = 0; i <= Q; ++i) {
            long long o = (long long)base * i;
            qoff[i] = (int)(o < n ? o : n);
        }
        qoff[Q] = n;
    }
    int nsmax = 2;
    for (int i = 0; i < Q; ++i) {
        const int nq = qoff[i + 1] - qoff[i];
        const int ns = (nq + 1) & ~1;
        if (ns > nsmax) nsmax = ns;
    }
    const size_t slab_bytes = (size_t)nsmax * 16 * sizeof(u32x2);
    const size_t feat_bytes = (size_t)n * 16 * sizeof(u32x2);   // fallbacks

    if (ws_size >= 2 * slab_bytes + wb_bytes + tab16_bytes) {
        u32x2* fA = (u32x2*)d_ws;
        u32x2* fB = (u32x2*)((char*)d_ws + slab_bytes);
        unsigned short* wb = (unsigned short*)((char*)d_ws + 2 * slab_bytes);
        u32* tab16 = (u32*)((char*)d_ws + 2 * slab_bytes + wb_bytes);

        hipLaunchKernelGGL(prep_weights, dim3(1), dim3(256), 0, stream, W1, W2, W3, wb);
        hipLaunchKernelGGL(cvt_table, dim3(8192), dim3(256), 0, stream,
                           table, tab16, total_entries);

        int prev_n = 0, prev_ns = 0, prev_off = 0;
        for (int i = 0; i < Q; ++i) {
            const int nq = qoff[i + 1] - qoff[i];
            const int ns = (nq + 1) & ~1;
            u32x2* cur = (i & 1) ? fB : fA;
            u32x2* prv = (i & 1) ? fA : fB;
            const int M = prev_n > 0 ? (prev_n + 127) / 128 : 0;
            if (nq <= 0) {
                // no encode work; flush pending mlp if any
                if (M > 0)
                    hipLaunchKernelGGL(mlp_mfma, dim3(M), dim3(256), 0, stream,
                                       prv, wb, b1, b2, b3, Wo, bo,
                                       out + prev_off, prev_n, prev_ns);
                prev_n = 0;
                continue;
            }
            const int bpl = (nq + 511) / 512;
            const int T = 16 * bpl + M;
            const int ilv = (M > 0 && 4 * M <= T) ? 1 : 0;
            hipLaunchKernelGGL(fused_q, dim3(T), dim3(256), 0, stream,
                               x + (size_t)3 * qoff[i], tab16, cur, nq, ns,
                               prv, wb, b1, b2, b3, Wo, bo,
                               out + prev_off, prev_n, prev_ns,
                               rv, dense_end, bpl, M, ilv);
            prev_n = nq; prev_ns = ns; prev_off = qoff[i];
        }
        if (prev_n > 0) {
            u32x2* last = ((Q - 1) & 1) ? fB : fA;
            const int M = (prev_n + 127) / 128;
            hipLaunchKernelGGL(mlp_mfma, dim3(M), dim3(256), 0, stream,
                               last, wb, b1, b2, b3, Wo, bo,
                               out + prev_off, prev_n, prev_ns);
        }
    } else if (ws_size >= feat_bytes + wb_bytes) {
        // ---- fallback: full fp32-split featT + MFMA mlp (R12 path) ----
        u32x2* featT = (u32x2*)d_ws;
        unsigned short* wb = (unsigned short*)((char*)d_ws + feat_bytes);

        hipLaunchKernelGGL(prep_weights, dim3(1), dim3(256), 0, stream, W1, W2, W3, wb);

        if (dense_end > 0)
            launch_encode(dense_end, x, table, featT, n, 0, rv, stream);
        for (int l = dense_end; l < 16; ++l)
            launch_encode(1, x, table, featT, n, l, rv, stream);

        const int nblocks = (n + 127) / 128;
        hipLaunchKernelGGL(mlp_mfma, dim3(nblocks), dim3(256), 0, stream,
                           featT, wb, b1, b2, b3, Wo, bo, out, n, n);
    } else if (ws_size >= feat_bytes) {
        u32x2* featT = (u32x2*)d_ws;
        if (dense_end > 0)
            launch_encode(dense_end, x, table, featT, n, 0, rv, stream);
        for (int l = dense_end; l < 16; ++l)
            launch_encode(1, x, table, featT, n, l, rv, stream);
        hipLaunchKernelGGL(mlp_forward, dim3((n + 255) / 256), dim3(256), 0, stream,
                           featT, W1, b1, W2, b2, W3, b3, Wo, bo, out, n);
    } else {
        hipLaunchKernelGGL(hashpinn_fused, dim3((n + 255) / 256), dim3(256), 0, stream,
                           x, table, W1, b1, W2, b2, W3, b3, Wo, bo, out, n, rv);
    }
}